// Round 1
// baseline (342.832 us; speedup 1.0000x reference)
//
#include <hip/hip_runtime.h>
#include <hip/hip_bf16.h>

#define R_RES 384
#define S_SEQ 128
#define CM 256
#define CC 32
#define CZ 128

typedef __attribute__((ext_vector_type(8))) short bf16x8;
typedef __attribute__((ext_vector_type(4))) float f32x4;
typedef __attribute__((ext_vector_type(4))) int i32x4;

__device__ __forceinline__ short tobf16(float f) {
    union { __hip_bfloat16 h; short s; } u;
    u.h = __float2bfloat16(f);
    return u.s;
}

// ---------------- kernel 0a: w_out (1024,128) f32 -> wbT (128,1024) bf16 ----------------
__global__ void k_transpose_wout(const float* __restrict__ w_out, short* __restrict__ wbT) {
    __shared__ float t[64][65];
    int k0 = blockIdx.x * 64;   // 16 blocks over k=1024
    int z0 = blockIdx.y * 64;   // 2 blocks over z=128
    int tid = threadIdx.x;
    int c = tid & 63, rg = tid >> 6;
#pragma unroll
    for (int rr = 0; rr < 16; ++rr) {
        int kk = rg * 16 + rr;
        t[kk][c] = w_out[(size_t)(k0 + kk) * CZ + z0 + c];
    }
    __syncthreads();
#pragma unroll
    for (int rr = 0; rr < 16; ++rr) {
        int zz = rg * 16 + rr;
        wbT[(size_t)(z0 + zz) * 1024 + k0 + c] = tobf16(t[c][zz]);
    }
}

// ---------------- kernel 0b: pack w1|w2 (256,32) -> wcT (64,256) bf16 ----------------
__global__ void k_pack_w12(const float* __restrict__ w1, const float* __restrict__ w2,
                           short* __restrict__ wcT) {
    int idx = blockIdx.x * 256 + threadIdx.x;   // 64 blocks -> 16384
    int k = idx >> 6, n = idx & 63;
    float v = (n < 32) ? w1[k * CC + n] : w2[k * CC + (n - 32)];
    wcT[n * CM + k] = tobf16(v);
}

// ---------------- kernel 1: LayerNorm + projections -> aT[m][s], bT[n][s] bf16 ----------------
// block = 256 thr (4 waves), grid = 768: blockIdx -> (r = b>>1, s0 = (b&1)*64)
__global__ __launch_bounds__(256) void k_ln_proj(
    const float* __restrict__ M, const float* __restrict__ ln_g, const float* __restrict__ ln_b,
    const float* __restrict__ b1, const float* __restrict__ b2,
    const short* __restrict__ wcT, short* __restrict__ aT, short* __restrict__ bT) {
    __shared__ short mnb[64 * 256];      // [s_loc][k] bf16, XOR-swizzled, 32 KB
    __shared__ short ab_s[2][32 * 72];   // [x][s_loc] stride-72 transpose buffers
    int r = blockIdx.x >> 1;
    int s0 = (blockIdx.x & 1) * 64;
    int tid = threadIdx.x, lane = tid & 63, w = tid >> 6;
    int g = lane >> 4, r16 = lane & 15;
    float4 gv = *(const float4*)(ln_g + lane * 4);
    float4 bv = *(const float4*)(ln_b + lane * 4);
    // phase A: LN, one wave per row
    for (int it = 0; it < 16; ++it) {
        int sl = it * 4 + w;   // 0..63
        float4 v = *(const float4*)(M + ((size_t)(s0 + sl) * R_RES + r) * CM + lane * 4);
        float sum = v.x + v.y + v.z + v.w;
        float sq = v.x * v.x + v.y * v.y + v.z * v.z + v.w * v.w;
#pragma unroll
        for (int off = 32; off; off >>= 1) {
            sum += __shfl_xor(sum, off);
            sq  += __shfl_xor(sq, off);
        }
        float mu = sum * (1.0f / 256.0f);
        float var = sq * (1.0f / 256.0f) - mu * mu;
        float rstd = rsqrtf(var + 1e-5f);
        short4 mnp;
        mnp.x = tobf16((v.x - mu) * rstd * gv.x + bv.x);
        mnp.y = tobf16((v.y - mu) * rstd * gv.y + bv.y);
        mnp.z = tobf16((v.z - mu) * rstd * gv.z + bv.z);
        mnp.w = tobf16((v.w - mu) * rstd * gv.w + bv.w);
        int byte = sl * 512 + lane * 8;
        byte ^= ((sl & 7) << 4);
        *(short4*)((char*)mnb + byte) = mnp;
    }
    __syncthreads();
    // phase B: GEMM mn(64x256) x wcT^T(256x64), wave w owns row-tile w
    f32x4 acc[4] = {{0,0,0,0},{0,0,0,0},{0,0,0,0},{0,0,0,0}};
    int srow = w * 16 + r16;
#pragma unroll
    for (int ks = 0; ks < 8; ++ks) {
        int byte = srow * 512 + ks * 64 + g * 16;
        byte ^= ((srow & 7) << 4);
        bf16x8 af = *(const bf16x8*)((const char*)mnb + byte);
#pragma unroll
        for (int nt = 0; nt < 4; ++nt) {
            bf16x8 bf = *(const bf16x8*)(wcT + (nt * 16 + r16) * CM + ks * 32 + g * 8);
            acc[nt] = __builtin_amdgcn_mfma_f32_16x16x32_bf16(af, bf, acc[nt], 0, 0, 0);
        }
    }
    // scatter (+bias, ->bf16) into transpose buffers
#pragma unroll
    for (int nt = 0; nt < 4; ++nt) {
        int n = nt * 16 + r16;
        int x = n & 31, sel = n >> 5;
        float bias = sel ? b2[x] : b1[x];
#pragma unroll
        for (int rr = 0; rr < 4; ++rr) {
            int sl = w * 16 + g * 4 + rr;
            ab_s[sel][x * 72 + sl] = tobf16(acc[nt][rr] + bias);
        }
    }
    __syncthreads();
    // coalesced write-out: aT[(r*32+x)][s0..s0+64), bT likewise
    int o = tid * 16;           // bytes over 4 KB chunk
    int x = o >> 7, sb = o & 127;
    i32x4 va = *(const i32x4*)((const char*)ab_s[0] + x * 144 + sb);
    i32x4 vb = *(const i32x4*)((const char*)ab_s[1] + x * 144 + sb);
    *(i32x4*)((char*)aT + (size_t)(r * 32 + x) * 256 + s0 * 2 + sb) = va;
    *(i32x4*)((char*)bT + (size_t)(r * 32 + x) * 256 + s0 * 2 + sb) = vb;
}

// ---------------- kernel 2: fused outer-product (K=S=128) + w_out contraction ----------------
// block = 256 thr (4 waves), grid = (96,96): bj = blockIdx.x, bi = blockIdx.y
__global__ __launch_bounds__(256) void k_opm(
    const short* __restrict__ aT, const short* __restrict__ bT,
    const short* __restrict__ wbT, const float* __restrict__ b_out,
    float* __restrict__ out) {
    __shared__ char smem[65536];   // [0,32K): A-strip, later A2; [32K,64K): B-strip
    int tid = threadIdx.x, lane = tid & 63, w = tid >> 6;
    int g = lane >> 4, r16 = lane & 15;
    int bj = blockIdx.x, bi = blockIdx.y;
    const char* gA = (const char*)(aT + (size_t)bi * 128 * 128);
    const char* gB = (const char*)(bT + (size_t)bj * 128 * 128);
    // stage strips with XOR swizzle (row = 256B)
#pragma unroll
    for (int it = 0; it < 8; ++it) {
        int o = (it * 256 + tid) * 16;
        int mrow = o >> 8;
        int so = o ^ ((mrow & 7) << 4);
        *(i32x4*)(smem + so) = *(const i32x4*)(gA + o);
        *(i32x4*)(smem + 32768 + so) = *(const i32x4*)(gB + o);
    }
    __syncthreads();
    // stage 2: O(128x128) = A-strip^T-dot over s; wave w -> cols [w*32, w*32+32)
    f32x4 acc[8][2] = {};
#pragma unroll
    for (int ks = 0; ks < 4; ++ks) {
        bf16x8 af[8];
#pragma unroll
        for (int mt = 0; mt < 8; ++mt) {
            int m = mt * 16 + r16;
            int byte = m * 256 + ks * 64 + g * 16;
            byte ^= ((m & 7) << 4);
            af[mt] = *(const bf16x8*)(smem + byte);
        }
#pragma unroll
        for (int nt = 0; nt < 2; ++nt) {
            int n = w * 32 + nt * 16 + r16;
            int byte = n * 256 + ks * 64 + g * 16;
            byte ^= ((n & 7) << 4);
            bf16x8 bf = *(const bf16x8*)(smem + 32768 + byte);
#pragma unroll
            for (int mt = 0; mt < 8; ++mt)
                acc[mt][nt] = __builtin_amdgcn_mfma_f32_16x16x32_bf16(af[mt], bf, acc[mt][nt], 0, 0, 0);
        }
    }
    __syncthreads();   // all strip reads done -> safe to overwrite [0,32K)
    // reorganize O -> A2 bf16 [p=i*4+j][k=x*32+y], swizzled
#pragma unroll
    for (int mt = 0; mt < 8; ++mt)
#pragma unroll
        for (int nt = 0; nt < 2; ++nt)
#pragma unroll
            for (int rr = 0; rr < 4; ++rr) {
                int m = mt * 16 + g * 4 + rr;        // i*32+x
                int n = w * 32 + nt * 16 + r16;      // j*32+y
                int p = ((m >> 5) << 2) + (n >> 5);
                int k = ((m & 31) << 5) + (n & 31);
                int byte = p * 2048 + k * 2;
                byte ^= ((p & 7) << 4);
                *(short*)(smem + byte) = tobf16(acc[mt][nt][rr]);
            }
    __syncthreads();
    // stage 3: out_pairs(16 x 128) = A2(16x1024) x wbT^T(1024x128); wave w -> z in [w*32, w*32+32)
    f32x4 acc3[2] = {{0,0,0,0},{0,0,0,0}};
#pragma unroll 4
    for (int ks2 = 0; ks2 < 32; ++ks2) {
        int byte = r16 * 2048 + ks2 * 64 + g * 16;
        byte ^= ((r16 & 7) << 4);
        bf16x8 a3 = *(const bf16x8*)(smem + byte);
#pragma unroll
        for (int nt = 0; nt < 2; ++nt) {
            int z = w * 32 + nt * 16 + r16;
            bf16x8 b3 = *(const bf16x8*)(wbT + (size_t)z * 1024 + ks2 * 32 + g * 8);
            acc3[nt] = __builtin_amdgcn_mfma_f32_16x16x32_bf16(a3, b3, acc3[nt], 0, 0, 0);
        }
    }
    // epilogue: (acc + b_out) / S
#pragma unroll
    for (int nt = 0; nt < 2; ++nt) {
        int z = w * 32 + nt * 16 + r16;
        float bo = b_out[z];
#pragma unroll
        for (int rr = 0; rr < 4; ++rr) {
            int p = g * 4 + rr;
            int ig = bi * 4 + (p >> 2);
            int jg = bj * 4 + (p & 3);
            out[((size_t)ig * R_RES + jg) * CZ + z] = (acc3[nt][rr] + bo) * (1.0f / 128.0f);
        }
    }
}

extern "C" void kernel_launch(void* const* d_in, const int* in_sizes, int n_in,
                              void* d_out, int out_size, void* d_ws, size_t ws_size,
                              hipStream_t stream) {
    const float* M     = (const float*)d_in[0];
    const float* ln_g  = (const float*)d_in[1];
    const float* ln_b  = (const float*)d_in[2];
    const float* w1    = (const float*)d_in[3];
    const float* b1    = (const float*)d_in[4];
    const float* w2    = (const float*)d_in[5];
    const float* b2    = (const float*)d_in[6];
    const float* w_out = (const float*)d_in[7];
    const float* b_out = (const float*)d_in[8];
    float* out = (float*)d_out;

    short* aT  = (short*)d_ws;              // 12288 x 128 bf16
    short* bT  = aT + 12288 * 128;          // 12288 x 128 bf16
    short* wbT = bT + 12288 * 128;          // 128 x 1024 bf16
    short* wcT = wbT + 128 * 1024;          // 64 x 256 bf16

    k_transpose_wout<<<dim3(16, 2), 256, 0, stream>>>(w_out, wbT);
    k_pack_w12<<<64, 256, 0, stream>>>(w1, w2, wcT);
    k_ln_proj<<<768, 256, 0, stream>>>(M, ln_g, ln_b, b1, b2, wcT, aT, bT);
    k_opm<<<dim3(96, 96), 256, 0, stream>>>(aT, bT, wbT, b_out, out);
}

// Round 2
// 237.644 us; speedup vs baseline: 1.4426x; 1.4426x over previous
//
#include <hip/hip_runtime.h>
#include <hip/hip_bf16.h>

#define R_RES 384
#define S_SEQ 128
#define CM 256
#define CC 32
#define CZ 128

typedef __attribute__((ext_vector_type(8))) short bf16x8;
typedef __attribute__((ext_vector_type(4))) float f32x4;
typedef __attribute__((ext_vector_type(4))) int i32x4;

__device__ __forceinline__ short tobf16(float f) {
    union { __hip_bfloat16 h; short s; } u;
    u.h = __float2bfloat16(f);
    return u.s;
}

// ---------------- kernel 0a: w_out (1024,128) f32 -> wbT (128,1024) bf16 ----------------
__global__ void k_transpose_wout(const float* __restrict__ w_out, short* __restrict__ wbT) {
    __shared__ float t[64][65];
    int k0 = blockIdx.x * 64;   // 16 blocks over k=1024
    int z0 = blockIdx.y * 64;   // 2 blocks over z=128
    int tid = threadIdx.x;
    int c = tid & 63, rg = tid >> 6;
#pragma unroll
    for (int rr = 0; rr < 16; ++rr) {
        int kk = rg * 16 + rr;
        t[kk][c] = w_out[(size_t)(k0 + kk) * CZ + z0 + c];
    }
    __syncthreads();
#pragma unroll
    for (int rr = 0; rr < 16; ++rr) {
        int zz = rg * 16 + rr;
        wbT[(size_t)(z0 + zz) * 1024 + k0 + c] = tobf16(t[c][zz]);
    }
}

// ---------------- kernel 0b: pack w1|w2 (256,32) -> wcT (64,256) bf16 ----------------
__global__ void k_pack_w12(const float* __restrict__ w1, const float* __restrict__ w2,
                           short* __restrict__ wcT) {
    int idx = blockIdx.x * 256 + threadIdx.x;   // 64 blocks -> 16384
    int k = idx >> 6, n = idx & 63;
    float v = (n < 32) ? w1[k * CC + n] : w2[k * CC + (n - 32)];
    wcT[n * CM + k] = tobf16(v);
}

// ---------------- kernel 1: LayerNorm + projections -> aT[m][s], bT[n][s] bf16 ----------------
// block = 256 thr (4 waves), grid = 768: blockIdx -> (r = b>>1, s0 = (b&1)*64)
__global__ __launch_bounds__(256) void k_ln_proj(
    const float* __restrict__ M, const float* __restrict__ ln_g, const float* __restrict__ ln_b,
    const float* __restrict__ b1, const float* __restrict__ b2,
    const short* __restrict__ wcT, short* __restrict__ aT, short* __restrict__ bT) {
    __shared__ short mnb[64 * 256];      // [s_loc][k] bf16, XOR-swizzled, 32 KB
    __shared__ short ab_s[2][32 * 72];   // [x][s_loc] stride-72 transpose buffers
    int r = blockIdx.x >> 1;
    int s0 = (blockIdx.x & 1) * 64;
    int tid = threadIdx.x, lane = tid & 63, w = tid >> 6;
    int g = lane >> 4, r16 = lane & 15;
    float4 gv = *(const float4*)(ln_g + lane * 4);
    float4 bv = *(const float4*)(ln_b + lane * 4);
    // phase A: LN, one wave per row
    for (int it = 0; it < 16; ++it) {
        int sl = it * 4 + w;   // 0..63
        float4 v = *(const float4*)(M + ((size_t)(s0 + sl) * R_RES + r) * CM + lane * 4);
        float sum = v.x + v.y + v.z + v.w;
        float sq = v.x * v.x + v.y * v.y + v.z * v.z + v.w * v.w;
#pragma unroll
        for (int off = 32; off; off >>= 1) {
            sum += __shfl_xor(sum, off);
            sq  += __shfl_xor(sq, off);
        }
        float mu = sum * (1.0f / 256.0f);
        float var = sq * (1.0f / 256.0f) - mu * mu;
        float rstd = rsqrtf(var + 1e-5f);
        short4 mnp;
        mnp.x = tobf16((v.x - mu) * rstd * gv.x + bv.x);
        mnp.y = tobf16((v.y - mu) * rstd * gv.y + bv.y);
        mnp.z = tobf16((v.z - mu) * rstd * gv.z + bv.z);
        mnp.w = tobf16((v.w - mu) * rstd * gv.w + bv.w);
        int byte = sl * 512 + lane * 8;
        byte ^= ((sl & 7) << 4);
        *(short4*)((char*)mnb + byte) = mnp;
    }
    __syncthreads();
    // phase B: GEMM mn(64x256) x wcT^T(256x64), wave w owns row-tile w
    f32x4 acc[4] = {{0,0,0,0},{0,0,0,0},{0,0,0,0},{0,0,0,0}};
    int srow = w * 16 + r16;
#pragma unroll
    for (int ks = 0; ks < 8; ++ks) {
        int byte = srow * 512 + ks * 64 + g * 16;
        byte ^= ((srow & 7) << 4);
        bf16x8 af = *(const bf16x8*)((const char*)mnb + byte);
#pragma unroll
        for (int nt = 0; nt < 4; ++nt) {
            bf16x8 bf = *(const bf16x8*)(wcT + (nt * 16 + r16) * CM + ks * 32 + g * 8);
            acc[nt] = __builtin_amdgcn_mfma_f32_16x16x32_bf16(af, bf, acc[nt], 0, 0, 0);
        }
    }
    // scatter (+bias, ->bf16) into transpose buffers
#pragma unroll
    for (int nt = 0; nt < 4; ++nt) {
        int n = nt * 16 + r16;
        int x = n & 31, sel = n >> 5;
        float bias = sel ? b2[x] : b1[x];
#pragma unroll
        for (int rr = 0; rr < 4; ++rr) {
            int sl = w * 16 + g * 4 + rr;
            ab_s[sel][x * 72 + sl] = tobf16(acc[nt][rr] + bias);
        }
    }
    __syncthreads();
    // coalesced write-out: aT[(r*32+x)][s0..s0+64), bT likewise
    int o = tid * 16;           // bytes over 4 KB chunk
    int x = o >> 7, sb = o & 127;
    i32x4 va = *(const i32x4*)((const char*)ab_s[0] + x * 144 + sb);
    i32x4 vb = *(const i32x4*)((const char*)ab_s[1] + x * 144 + sb);
    *(i32x4*)((char*)aT + (size_t)(r * 32 + x) * 256 + s0 * 2 + sb) = va;
    *(i32x4*)((char*)bT + (size_t)(r * 32 + x) * 256 + s0 * 2 + sb) = vb;
}

// ---------------- kernel 2: fused outer-product (K=S=128) + w_out contraction ----------------
// block = 512 thr (8 waves), grid = (96, 48): bj = blockIdx.x (4 res), bi = blockIdx.y (8 res)
// O-tile 256x128; LDS 64KB shared between A-strip [256][128]bf16 and A2 [32][1024]bf16.
__global__ __launch_bounds__(512, 4) void k_opm(
    const short* __restrict__ aT, const short* __restrict__ bT,
    const short* __restrict__ wbT, const float* __restrict__ b_out,
    float* __restrict__ out) {
    __shared__ __align__(16) char smem[65536];
    int tid = threadIdx.x, lane = tid & 63, w = tid >> 6;
    int g = lane >> 4, r16 = lane & 15;
    int wm = w >> 1, wn = w & 1;      // stage-2 wave split: m 4x64, n 2x64
    int bj = blockIdx.x, bi = blockIdx.y;
    const char* gA = (const char*)(aT + (size_t)bi * 256 * 128);
    const char* gB = (const char*)(bT + (size_t)bj * 128 * 128);

    // ---- phase 1: async-stage A-strip (64KB) via global_load_lds, inverse-swizzled source
#pragma unroll
    for (int it = 0; it < 8; ++it) {
        int q = w * 8192 + it * 1024 + lane * 16;            // linear LDS dest
        int o = q ^ (((q >> 8) & 7) << 4);                   // inverse (=same) XOR on source
        __builtin_amdgcn_global_load_lds(
            (const __attribute__((address_space(1))) void*)(gA + o),
            (__attribute__((address_space(3))) void*)(smem + w * 8192 + it * 1024),
            16, 0, 0);
    }
    __syncthreads();

    // ---- phase 2: O[256x128] outer-product GEMM, K=S=128. B straight from global (L2-hot).
    // operand-swapped mfma(b,a): lane holds O[m = wm*64+mi*16+r16][n = wn*64+ni*16+g*4+rr]
    f32x4 acc[4][4] = {};
#pragma unroll
    for (int ks = 0; ks < 4; ++ks) {
        bf16x8 bfr[4];
#pragma unroll
        for (int ni = 0; ni < 4; ++ni) {
            int n = wn * 64 + ni * 16 + r16;
            bfr[ni] = *(const bf16x8*)(gB + n * 256 + ks * 64 + g * 16);
        }
#pragma unroll
        for (int mi = 0; mi < 4; ++mi) {
            int m = wm * 64 + mi * 16 + r16;
            int byte = (m * 256 + ks * 64 + g * 16) ^ ((m & 7) << 4);
            bf16x8 af = *(const bf16x8*)(smem + byte);
#pragma unroll
            for (int ni = 0; ni < 4; ++ni)
                acc[mi][ni] = __builtin_amdgcn_mfma_f32_16x16x32_bf16(bfr[ni], af, acc[mi][ni], 0, 0, 0);
        }
    }
    __syncthreads();   // all A-strip reads done -> reuse region for A2

    // ---- phase 3: reorg O -> A2 bf16 [p=0..31][k=x*32+y], 8B writes, dual XOR swizzle
#pragma unroll
    for (int mi = 0; mi < 4; ++mi)
#pragma unroll
        for (int ni = 0; ni < 4; ++ni) {
            int p = (wm * 2 + (mi >> 1)) * 4 + wn * 2 + (ni >> 1);
            int x = (mi & 1) * 16 + r16;
            int y0 = (ni & 1) * 16 + g * 4;
            int byte = p * 2048 + x * 64 + y0 * 2;
            byte ^= (((p & 7) ^ (x & 7)) << 4);
            short4 pk;
            pk.x = tobf16(acc[mi][ni][0]);
            pk.y = tobf16(acc[mi][ni][1]);
            pk.z = tobf16(acc[mi][ni][2]);
            pk.w = tobf16(acc[mi][ni][3]);
            *(short4*)(smem + byte) = pk;
        }
    __syncthreads();

    // ---- phase 4: out[32 p][128 z] = A2(32x1024) x wbT^T(1024x128); wave w -> z in [w*16, +16)
    f32x4 acc3[2] = {{0,0,0,0},{0,0,0,0}};
    int z = w * 16 + r16;
    float bo = b_out[z];
#pragma unroll 8
    for (int ks2 = 0; ks2 < 32; ++ks2) {
        int sw = ((r16 & 7) ^ (ks2 & 7)) << 4;
        bf16x8 a30 = *(const bf16x8*)(smem + ((r16 * 2048 + ks2 * 64 + g * 16) ^ sw));
        bf16x8 a31 = *(const bf16x8*)(smem + (((16 + r16) * 2048 + ks2 * 64 + g * 16) ^ sw));
        bf16x8 b3 = *(const bf16x8*)(wbT + (size_t)z * 1024 + ks2 * 32 + g * 8);
        acc3[0] = __builtin_amdgcn_mfma_f32_16x16x32_bf16(a30, b3, acc3[0], 0, 0, 0);
        acc3[1] = __builtin_amdgcn_mfma_f32_16x16x32_bf16(a31, b3, acc3[1], 0, 0, 0);
    }
    // ---- epilogue: (acc + b_out) / S
#pragma unroll
    for (int pt = 0; pt < 2; ++pt)
#pragma unroll
        for (int rr = 0; rr < 4; ++rr) {
            int p = pt * 16 + g * 4 + rr;
            int ig = bi * 8 + (p >> 2);
            int jg = bj * 4 + (p & 3);
            out[((size_t)ig * R_RES + jg) * CZ + z] = (acc3[pt][rr] + bo) * (1.0f / 128.0f);
        }
}

extern "C" void kernel_launch(void* const* d_in, const int* in_sizes, int n_in,
                              void* d_out, int out_size, void* d_ws, size_t ws_size,
                              hipStream_t stream) {
    const float* M     = (const float*)d_in[0];
    const float* ln_g  = (const float*)d_in[1];
    const float* ln_b  = (const float*)d_in[2];
    const float* w1    = (const float*)d_in[3];
    const float* b1    = (const float*)d_in[4];
    const float* w2    = (const float*)d_in[5];
    const float* b2    = (const float*)d_in[6];
    const float* w_out = (const float*)d_in[7];
    const float* b_out = (const float*)d_in[8];
    float* out = (float*)d_out;

    short* aT  = (short*)d_ws;              // 12288 x 128 bf16
    short* bT  = aT + 12288 * 128;          // 12288 x 128 bf16
    short* wbT = bT + 12288 * 128;          // 128 x 1024 bf16
    short* wcT = wbT + 128 * 1024;          // 64 x 256 bf16

    k_transpose_wout<<<dim3(16, 2), 256, 0, stream>>>(w_out, wbT);
    k_pack_w12<<<64, 256, 0, stream>>>(w1, w2, wcT);
    k_ln_proj<<<768, 256, 0, stream>>>(M, ln_g, ln_b, b1, b2, wcT, aT, bT);
    k_opm<<<dim3(96, 48), 512, 0, stream>>>(aT, bT, wbT, b_out, out);
}